// Round 2
// baseline (17555.423 us; speedup 1.0000x reference)
//
#include <hip/hip_runtime.h>
#include <hip/hip_bf16.h>

// RQ-VAE forward, fp32 baseline, row-chunked (8 x 8192 rows) to cap workspace
// at ~120 MiB (round-1 core dump was most likely d_ws overflow at ~960 MiB).
// Encoder MLP -> residual quantize (4 levels x 256 codes x 128 dims) -> decoder MLP.
// All GEMMs fp32 vector (no fp32 MFMA on CDNA4). 128x128 tile, BK=16, 256 thr, 8x8/thread.

#define MC 8192            // rows per chunk
#define NCHUNK 8           // 65536 / MC

// ---------------- GEMM: C = A@W + bias, optional ReLU ----------------
// A: [M,K] row-major, W: [K,N] row-major, C: [M,N] row-major.
// Requires M%128==0, N%128==0, K%16==0 (true for all layers here).
template<int RELU>
__global__ __launch_bounds__(256, 4)
void gemm_bias(const float* __restrict__ A, const float* __restrict__ W,
               const float* __restrict__ bias, float* __restrict__ C,
               int M, int N, int K)
{
    __shared__ float As[16 * 128];   // k-major: As[k][row]
    __shared__ float Bs[16 * 128];   // Bs[k][col]
    const int tid = threadIdx.x;
    const int tx = tid & 15;         // col group
    const int ty = tid >> 4;         // row group
    const size_t arow = (size_t)blockIdx.y * 128;
    const int bcol = blockIdx.x * 128;

    const int arA = tid >> 2;        // 0..63 (row within half-tile)
    const int akc = (tid & 3) << 2;  // 0,4,8,12 (k offset)
    const int bkr = tid >> 5;        // 0..7 (k row)
    const int bc  = (tid & 31) << 2; // 0..124 (col)

    float acc[8][8] = {};

    for (int k0 = 0; k0 < K; k0 += 16) {
        __syncthreads();
        float4 a0 = *(const float4*)(A + (arow + arA) * K + k0 + akc);
        float4 a1 = *(const float4*)(A + (arow + 64 + arA) * K + k0 + akc);
        float4 b0 = *(const float4*)(W + (size_t)(k0 + bkr) * N + bcol + bc);
        float4 b1 = *(const float4*)(W + (size_t)(k0 + 8 + bkr) * N + bcol + bc);
        // A stored transposed (k-major). 2 lanes/bank on writes -> free.
        As[(akc + 0) * 128 + arA] = a0.x;
        As[(akc + 1) * 128 + arA] = a0.y;
        As[(akc + 2) * 128 + arA] = a0.z;
        As[(akc + 3) * 128 + arA] = a0.w;
        As[(akc + 0) * 128 + 64 + arA] = a1.x;
        As[(akc + 1) * 128 + 64 + arA] = a1.y;
        As[(akc + 2) * 128 + 64 + arA] = a1.z;
        As[(akc + 3) * 128 + 64 + arA] = a1.w;
        *(float4*)&Bs[bkr * 128 + bc] = b0;
        *(float4*)&Bs[(bkr + 8) * 128 + bc] = b1;
        __syncthreads();
        #pragma unroll
        for (int k = 0; k < 16; ++k) {
            // micro-tile rows {4ty..4ty+3, 64+4ty..}, cols {4tx..4tx+3, 64+4tx..}
            // (split +64 keeps LDS reads 2-way max -> free)
            float4 x0 = *(float4*)&As[k * 128 + 4 * ty];
            float4 x1 = *(float4*)&As[k * 128 + 64 + 4 * ty];
            float4 y0 = *(float4*)&Bs[k * 128 + 4 * tx];
            float4 y1 = *(float4*)&Bs[k * 128 + 64 + 4 * tx];
            float ax[8] = {x0.x, x0.y, x0.z, x0.w, x1.x, x1.y, x1.z, x1.w};
            float by[8] = {y0.x, y0.y, y0.z, y0.w, y1.x, y1.y, y1.z, y1.w};
            #pragma unroll
            for (int i = 0; i < 8; ++i)
                #pragma unroll
                for (int j = 0; j < 8; ++j)
                    acc[i][j] = fmaf(ax[i], by[j], acc[i][j]);
        }
    }

    float4 bias0 = *(const float4*)(bias + bcol + 4 * tx);
    float4 bias1 = *(const float4*)(bias + bcol + 64 + 4 * tx);
    float bj[8] = {bias0.x, bias0.y, bias0.z, bias0.w, bias1.x, bias1.y, bias1.z, bias1.w};
    #pragma unroll
    for (int i = 0; i < 8; ++i) {
        int r = (i < 4) ? (4 * ty + i) : (64 + 4 * ty + i - 4);
        size_t off = (arow + r) * (size_t)N + bcol;
        float v[8];
        #pragma unroll
        for (int j = 0; j < 8; ++j) {
            v[j] = acc[i][j] + bj[j];
            if (RELU) v[j] = fmaxf(v[j], 0.f);
        }
        *(float4*)(C + off + 4 * tx)      = make_float4(v[0], v[1], v[2], v[3]);
        *(float4*)(C + off + 64 + 4 * tx) = make_float4(v[4], v[5], v[6], v[7]);
    }
}

// ---------------- Residual quantizer ----------------
// Block = 256 thr (4 waves), owns 32 rows of this chunk. Residual [32][128] in LDS.
// Per level: codebook staged in 4 chunks of 64 codes (pad 132 floats/code),
// phase A: lane=code, d2_rel = |c|^2 - 2 r.c (|r|^2 constant per row -> argmin-safe),
// butterfly min with first-min tie-break (matches jnp.argmin).
// Phase B: lane=dims, q read from global (L2-hot), residual update + loss accum.
// loss_l = 1.25 * sum(|r_next|^2); x_q = z - r_final.
// Also writes z (scalar stores: z_out slot in d_out is only 4B-aligned) and indices.
__global__ __launch_bounds__(256)
void rq_kernel(const float* __restrict__ z, const float* __restrict__ cbs,
               float* __restrict__ xq, float* __restrict__ idx_out,
               float* __restrict__ z_out, float* __restrict__ partials)
{
    __shared__ float cbt[64 * 132];
    __shared__ float csq[64];
    __shared__ float res[32][128];
    const int tid = threadIdx.x;
    const int wave = tid >> 6;
    const int lane = tid & 63;
    const size_t row0 = (size_t)blockIdx.x * 32;
    const int myrow = wave * 8;

    {   // residual := z ; also mirror z into d_out's z slot (scalar: 4B-aligned dest)
        const float4* z4 = (const float4*)(z + row0 * 128);
        float4* r4 = (float4*)res;
        for (int i = tid; i < 32 * 32; i += 256) r4[i] = z4[i];
        const float* zs = z + row0 * 128;
        float* zd = z_out + row0 * 128;
        for (int i = tid; i < 32 * 128; i += 256) zd[i] = zs[i];
    }

    float lacc[4] = {0.f, 0.f, 0.f, 0.f};

    #pragma unroll
    for (int l = 0; l < 4; ++l) {
        float bestv[8];
        int   besti[8];
        #pragma unroll
        for (int r = 0; r < 8; ++r) { bestv[r] = 3.4e38f; besti[r] = 0; }

        for (int ch = 0; ch < 4; ++ch) {
            __syncthreads();
            const float4* src = (const float4*)(cbs + ((size_t)l * 256 + ch * 64) * 128);
            for (int i = tid; i < 64 * 32; i += 256) {
                int code = i >> 5, dc = (i & 31) << 2;
                *(float4*)&cbt[code * 132 + dc] = src[i];
            }
            __syncthreads();
            if (tid < 64) {
                float s = 0.f;
                for (int d = 0; d < 128; d += 4) {
                    float4 c = *(float4*)&cbt[tid * 132 + d];
                    s += c.x * c.x + c.y * c.y + c.z * c.z + c.w * c.w;
                }
                csq[tid] = s;
            }
            __syncthreads();

            float dot[8] = {};
            for (int d = 0; d < 128; d += 4) {
                float4 c = *(float4*)&cbt[lane * 132 + d];   // lane = code
                #pragma unroll
                for (int r = 0; r < 8; ++r) {
                    float4 rv = *(float4*)&res[myrow + r][d]; // broadcast
                    dot[r] += c.x * rv.x + c.y * rv.y + c.z * rv.z + c.w * rv.w;
                }
            }
            #pragma unroll
            for (int r = 0; r < 8; ++r) {
                float s = csq[lane] - 2.f * dot[r];
                int idx = ch * 64 + lane;
                #pragma unroll
                for (int off = 32; off > 0; off >>= 1) {
                    float ov = __shfl_xor(s, off, 64);
                    int   oi = __shfl_xor(idx, off, 64);
                    if (ov < s || (ov == s && oi < idx)) { s = ov; idx = oi; }
                }
                // chunks ascend in code index -> strict < keeps first-min
                if (s < bestv[r]) { bestv[r] = s; besti[r] = idx; }
            }
        }
        // phase B
        #pragma unroll
        for (int r = 0; r < 8; ++r) {
            int k = besti[r];
            const float2 qv = *(const float2*)(cbs + ((size_t)l * 256 + k) * 128 + lane * 2);
            float2 rv = *(float2*)&res[myrow + r][lane * 2];
            rv.x -= qv.x; rv.y -= qv.y;
            *(float2*)&res[myrow + r][lane * 2] = rv;
            lacc[l] += rv.x * rv.x + rv.y * rv.y;
            if (lane == 0) idx_out[(row0 + myrow + r) * 4 + l] = (float)k;
        }
    }

    __syncthreads();
    {   // x_q = z - r_final
        const float4* z4 = (const float4*)(z + row0 * 128);
        const float4* r4 = (const float4*)res;
        float4* q4 = (float4*)(xq + row0 * 128);
        for (int i = tid; i < 32 * 32; i += 256) {
            float4 zv = z4[i], rv = r4[i];
            q4[i] = make_float4(zv.x - rv.x, zv.y - rv.y, zv.z - rv.z, zv.w - rv.w);
        }
    }
    #pragma unroll
    for (int l = 0; l < 4; ++l) {
        float v = lacc[l];
        #pragma unroll
        for (int off = 32; off > 0; off >>= 1) v += __shfl_xor(v, off, 64);
        if (lane == 0) atomicAdd(&partials[l], v);
    }
}

__global__ void zero_partials(float* __restrict__ partials)
{
    if (threadIdx.x < 4) partials[threadIdx.x] = 0.f;
}

__global__ void finalize_loss(const float* __restrict__ partials, float* __restrict__ out)
{
    // rq_loss = mean_l[ 1.25 * mean_elems(|r_next|^2) ]
    out[0] = (partials[0] + partials[1] + partials[2] + partials[3])
             * (1.25f / (4.f * 65536.f * 128.f));
}

extern "C" void kernel_launch(void* const* d_in, const int* in_sizes, int n_in,
                              void* d_out, int out_size, void* d_ws, size_t ws_size,
                              hipStream_t stream)
{
    // setup_inputs() dict order: x, then (W,b) interleaved per layer for enc, dec, then codebooks.
    const float* x   = (const float*)d_in[0];
    const float* eW0 = (const float*)d_in[1];
    const float* eb0 = (const float*)d_in[2];
    const float* eW1 = (const float*)d_in[3];
    const float* eb1 = (const float*)d_in[4];
    const float* eW2 = (const float*)d_in[5];
    const float* eb2 = (const float*)d_in[6];
    const float* eW3 = (const float*)d_in[7];
    const float* eb3 = (const float*)d_in[8];
    const float* dW0 = (const float*)d_in[9];
    const float* db0 = (const float*)d_in[10];
    const float* dW1 = (const float*)d_in[11];
    const float* db1 = (const float*)d_in[12];
    const float* dW2 = (const float*)d_in[13];
    const float* db2 = (const float*)d_in[14];
    const float* dW3 = (const float*)d_in[15];
    const float* db3 = (const float*)d_in[16];
    const float* cbs = (const float*)d_in[17];

    float* out = (float*)d_out;
    const size_t LOSS_OFF = (size_t)65536 * 768;          // 50331648
    const size_t IDX_OFF  = LOSS_OFF + 1;                 // 50331649
    const size_t Z_OFF    = IDX_OFF + (size_t)65536 * 4;  // 50593793 (only 4B-aligned!)

    // Workspace (per-chunk buffers): 64 + 32 + 16 + 4 + 4 MiB + 16 B ~= 120 MiB.
    float* ws = (float*)d_ws;
    float* h0 = ws;                        // MC x 2048 (enc h0 / dec d2)
    float* h1 = h0 + (size_t)MC * 2048;    // MC x 1024 (enc h1 / dec d1)
    float* h2 = h1 + (size_t)MC * 1024;    // MC x 512  (enc h2 / dec d0)
    float* zb = h2 + (size_t)MC * 512;     // MC x 128  (aligned z)
    float* xq = zb + (size_t)MC * 128;     // MC x 128
    float* partials = xq + (size_t)MC * 128; // 4 floats

    dim3 blk(256);
    zero_partials<<<dim3(1), dim3(64), 0, stream>>>(partials);

    for (int c = 0; c < NCHUNK; ++c) {
        const float* xc = x + (size_t)c * MC * 768;
        float* outc = out + (size_t)c * MC * 768;
        // encoder
        gemm_bias<1><<<dim3(2048 / 128, MC / 128), blk, 0, stream>>>(xc, eW0, eb0, h0, MC, 2048, 768);
        gemm_bias<1><<<dim3(1024 / 128, MC / 128), blk, 0, stream>>>(h0, eW1, eb1, h1, MC, 1024, 2048);
        gemm_bias<1><<<dim3(512 / 128,  MC / 128), blk, 0, stream>>>(h1, eW2, eb2, h2, MC, 512, 1024);
        gemm_bias<0><<<dim3(128 / 128,  MC / 128), blk, 0, stream>>>(h2, eW3, eb3, zb, MC, 128, 512);
        // residual quantize (+ writes z and indices into d_out)
        rq_kernel<<<dim3(MC / 32), blk, 0, stream>>>(
            zb, cbs, xq,
            out + IDX_OFF + (size_t)c * MC * 4,
            out + Z_OFF + (size_t)c * MC * 128,
            partials);
        // decoder
        gemm_bias<1><<<dim3(512 / 128,  MC / 128), blk, 0, stream>>>(xq, dW0, db0, h2, MC, 512, 128);
        gemm_bias<1><<<dim3(1024 / 128, MC / 128), blk, 0, stream>>>(h2, dW1, db1, h1, MC, 1024, 512);
        gemm_bias<1><<<dim3(2048 / 128, MC / 128), blk, 0, stream>>>(h1, dW2, db2, h0, MC, 2048, 1024);
        gemm_bias<0><<<dim3(768 / 128,  MC / 128), blk, 0, stream>>>(h0, dW3, db3, outc, MC, 768, 2048);
    }

    finalize_loss<<<dim3(1), dim3(1), 0, stream>>>(partials, out + LOSS_OFF);
}